// Round 12
// baseline (130.805 us; speedup 1.0000x reference)
//
#include <hip/hip_runtime.h>
#include <hip/hip_bf16.h>
#include <math.h>

#define BATCH 64
#define TT 512
#define HH 1024
#define KK 8
#define ROWS (BATCH * TT)          // 32768
#define SEG  (ROWS * KK)           // 262144 floats per logits output
#define TAGS_OFF (3 * SEG)         // 786432
#define LOSS_OFF (TAGS_OFF + BATCH * 3 * TT)  // 884736

// ---------------------------------------------------------------------------
// Kernel 1: fused 3-head GEMM (R11, proven DS-throughput-bound; unchanged
// except it<31 guard fix). 512 blocks x 4 waves, wave = K-quarter, per-wave
// private double-buffered tiles, lane=(r16,q4), hh-XOR-swizzled weight tile.
// ---------------------------------------------------------------------------
__global__ __launch_bounds__(256, 2) void gemm_heads(
    const float* __restrict__ enc,
    const float* __restrict__ Wt, const float* __restrict__ bt,
    const float* __restrict__ Wp, const float* __restrict__ bpv,
    const float* __restrict__ Wm, const float* __restrict__ bm,
    float* __restrict__ out)
{
    __shared__ float xt[4][2][16][68];    // 34.8 KB per-wave x tiles (padded)
    __shared__ float wl[4][2][16][32];    // 16.4 KB per-wave weight tiles
    __shared__ float biasl[24];

    int tid  = threadIdx.x;
    int lane = tid & 63;
    int w    = __builtin_amdgcn_readfirstlane(tid >> 6);  // K-quarter 0..3
    int r    = lane >> 2;
    int q    = lane & 3;
    int rowblk = blockIdx.x * 64;

    if (tid < 24) {
        int hd = tid >> 3, cl = tid & 7;
        biasl[tid] = (hd == 0) ? bt[cl] : (hd == 1) ? bpv[cl] : bm[cl];
    }

    const float* encw = enc + (size_t)rowblk * HH + w * 256;
    const float* Wkt = Wt + w * 2048;
    const float* Wkp = Wp + w * 2048;
    const float* Wkm = Wm + w * 2048;

    int srow = lane >> 2;
    int schunk = lane & 3;

    float acc[24];
#pragma unroll
    for (int c = 0; c < 24; ++c) acc[c] = 0.f;

    float4 sreg[4];
    float  wreg[6];

#define LOADT(it)                                                             \
    {                                                                         \
        _Pragma("unroll")                                                     \
        for (int i = 0; i < 4; ++i)                                           \
            sreg[i] = *(const float4*)(encw + (size_t)(srow + 16 * i) * HH +  \
                                       (it) * 16 + schunk * 4);               \
    }
#define WRITET(buf)                                                           \
    {                                                                         \
        _Pragma("unroll")                                                     \
        for (int i = 0; i < 4; ++i) {                                         \
            xt[w][buf][schunk * 4 + 0][srow + 16 * i] = sreg[i].x;            \
            xt[w][buf][schunk * 4 + 1][srow + 16 * i] = sreg[i].y;            \
            xt[w][buf][schunk * 4 + 2][srow + 16 * i] = sreg[i].z;            \
            xt[w][buf][schunk * 4 + 3][srow + 16 * i] = sreg[i].w;            \
        }                                                                     \
    }
#define WLOADG(it)                                                            \
    {                                                                         \
        wreg[0] = Wkt[(it) * 128 + lane]; wreg[1] = Wkt[(it) * 128 + 64 + lane]; \
        wreg[2] = Wkp[(it) * 128 + lane]; wreg[3] = Wkp[(it) * 128 + 64 + lane]; \
        wreg[4] = Wkm[(it) * 128 + lane]; wreg[5] = Wkm[(it) * 128 + 64 + lane]; \
    }
#define WWRITE(buf)                                                           \
    {                                                                         \
        int col_ = lane & 7;                                                  \
        _Pragma("unroll")                                                     \
        for (int i = 0; i < 6; ++i) {                                         \
            int hh_ = (lane >> 3) + 8 * (i & 1);                              \
            int c_  = 8 * (i >> 1) + col_;                                    \
            int q_  = (c_ * 43) >> 8;                                         \
            int s_  = c_ - 6 * q_;                                            \
            wl[w][buf][hh_][8 * (q_ ^ (hh_ & 3)) + s_] = wreg[i];             \
        }                                                                     \
    }

    LOADT(0)
    WLOADG(0)
    WRITET(0)
    WWRITE(0)

    for (int it = 0; it < 16; ++it) {
        int cb = it & 1;
        if (it < 15) {
            LOADT(it + 1)
            WLOADG(it + 1)
        }
#pragma unroll
        for (int hh = 0; hh < 16; ++hh) {
            float4 xv = *(const float4*)&xt[w][cb][hh][4 * r];
            const float* wp_ = &wl[w][cb][hh][8 * (q ^ (hh & 3))];
            float4 w0 = *(const float4*)wp_;
            float2 w1 = *(const float2*)(wp_ + 4);
#pragma unroll
            for (int j = 0; j < 4; ++j) {
                float xe = (j == 0) ? xv.x : (j == 1) ? xv.y : (j == 2) ? xv.z : xv.w;
                acc[j * 6 + 0] = fmaf(xe, w0.x, acc[j * 6 + 0]);
                acc[j * 6 + 1] = fmaf(xe, w0.y, acc[j * 6 + 1]);
                acc[j * 6 + 2] = fmaf(xe, w0.z, acc[j * 6 + 2]);
                acc[j * 6 + 3] = fmaf(xe, w0.w, acc[j * 6 + 3]);
                acc[j * 6 + 4] = fmaf(xe, w1.x, acc[j * 6 + 4]);
                acc[j * 6 + 5] = fmaf(xe, w1.y, acc[j * 6 + 5]);
            }
        }
        if (it < 15) {
            WRITET(cb ^ 1)
            WWRITE(cb ^ 1)
        }
    }
#undef LOADT
#undef WRITET
#undef WLOADG
#undef WWRITE

    // ---- 4-way K-quarter reduce + coalesced store via LDS overlay --------
    __syncthreads();
    float* xf = &xt[0][0][0][0];
    int myrow = 4 * r;
    if (w != 0) {
        float* sl = xf + w * 1600;
#pragma unroll
        for (int j = 0; j < 4; ++j)
#pragma unroll
            for (int s = 0; s < 6; ++s)
                sl[(myrow + j) * 25 + q * 6 + s] = acc[j * 6 + s];
    }
    __syncthreads();
    if (w == 0) {
#pragma unroll
        for (int j = 0; j < 4; ++j)
#pragma unroll
            for (int s = 0; s < 6; ++s)
                xf[(myrow + j) * 25 + q * 6 + s] =
                    acc[j * 6 + s] + xf[1600 + (myrow + j) * 25 + q * 6 + s]
                                   + xf[3200 + (myrow + j) * 25 + q * 6 + s]
                                   + xf[4800 + (myrow + j) * 25 + q * 6 + s];
    }
    __syncthreads();
#pragma unroll
    for (int i = 0; i < 2; ++i) {
        int flat = tid + 256 * i;
        if (flat < 384) {
            int seg  = flat >> 7;
            int rem  = flat & 127;
            int row  = rem >> 1;
            int half = rem & 1;
            float4 v;
            v.x = xf[row * 25 + seg * 8 + half * 4 + 0] + biasl[seg * 8 + half * 4 + 0];
            v.y = xf[row * 25 + seg * 8 + half * 4 + 1] + biasl[seg * 8 + half * 4 + 1];
            v.z = xf[row * 25 + seg * 8 + half * 4 + 2] + biasl[seg * 8 + half * 4 + 2];
            v.w = xf[row * 25 + seg * 8 + half * 4 + 3] + biasl[seg * 8 + half * 4 + 3];
            *(float4*)(out + (size_t)seg * SEG + (size_t)(rowblk + row) * 8 + half * 4) = v;
        }
    }
}

// ---------------------------------------------------------------------------
// Pure-VALU cross-lane helpers
// ---------------------------------------------------------------------------
#define DPPF(x, ctrl) __int_as_float(__builtin_amdgcn_update_dpp(              \
    0, __float_as_int(x), ctrl, 0xF, 0xF, true))
#define SWIZF(x, pat) __int_as_float(__builtin_amdgcn_ds_swizzle(              \
    __float_as_int(x), pat))
#define BPERMF(a, x)  __int_as_float(__builtin_amdgcn_ds_bpermute(             \
    a, __float_as_int(x)))

__device__ __forceinline__ float rfl(float x) {
    return __int_as_float(__builtin_amdgcn_readfirstlane(__float_as_int(x)));
}

#if __has_builtin(__builtin_amdgcn_permlane16_swap)
__device__ __forceinline__ float xor16f(float x, int lane) {
    typedef unsigned uv2 __attribute__((ext_vector_type(2)));
    uv2 r = __builtin_amdgcn_permlane16_swap(__float_as_uint(x), __float_as_uint(x), false, false);
    return __uint_as_float((lane & 16) ? r.x : r.y);
}
#else
__device__ __forceinline__ float xor16f(float x, int lane) { return SWIZF(x, 0x401F); }
#endif

#if __has_builtin(__builtin_amdgcn_permlane32_swap)
__device__ __forceinline__ float xor32f(float x, int lane) {
    typedef unsigned uv2 __attribute__((ext_vector_type(2)));
    uv2 r = __builtin_amdgcn_permlane32_swap(__float_as_uint(x), __float_as_uint(x), false, false);
    return __uint_as_float((lane & 32) ? r.x : r.y);
}
#else
__device__ __forceinline__ float xor32f(float x, int lane) {
    return BPERMF(((lane ^ 32) << 2), x);
}
#endif

// ---------------------------------------------------------------------------
// Kernel 2: 96 blocks x 128 threads. Block owns TWO sequences (s0=2blk,
// s1=2blk+1). Wave 0: Viterbi for both, interleaved (2 independent chains ->
// ILP); wave 1: both multiplicative LSEs + scores. lt reads go through a
// 6-step-deep register pipeline (3 iterations ahead) so the ~120-cyc
// ds_read_b32 latency is off the recurrence chain (R11 post-mortem: 2-step
// prefetch left ~60 cyc/step of LDS latency exposed).
// ---------------------------------------------------------------------------
__global__ __launch_bounds__(128) void crf_vit(
    const float* __restrict__ logits,
    const int* __restrict__ labels,
    const int* __restrict__ lens,
    const float* __restrict__ trans_t,
    const float* __restrict__ trans_p,
    const float* __restrict__ trans_m,
    float* __restrict__ out_tags,
    float* __restrict__ partial)
{
    __shared__ float llds[2][TT * KK];      // 32 KB
    __shared__ unsigned bpw[2][TT * 2];     // 8 KB
    __shared__ unsigned fmapw[2][64][2];
    __shared__ unsigned char bnd[2][64];

    int blk = blockIdx.x;                   // 0..95
    int sA = 2 * blk, sB = 2 * blk + 1;
    int hA = sA >> 6, bA = sA & 63;
    int hB = sB >> 6, bB = sB & 63;
    int tid = threadIdx.x;
    int wid = __builtin_amdgcn_readfirstlane(tid >> 6);
    int lane = tid & 63;
    int hi = lane >> 3, lo = lane & 7;

    // stage both sequences' logits
    {
        const float4* LvA = (const float4*)(logits + ((size_t)hA * BATCH + bA) * (TT * KK));
        const float4* LvB = (const float4*)(logits + ((size_t)hB * BATCH + bB) * (TT * KK));
        float4* lvA = (float4*)llds[0];
        float4* lvB = (float4*)llds[1];
#pragma unroll
        for (int i = 0; i < 8; ++i) lvA[tid + 128 * i] = LvA[tid + 128 * i];
#pragma unroll
        for (int i = 0; i < 8; ++i) lvB[tid + 128 * i] = LvB[tid + 128 * i];
    }
    __syncthreads();

    const float* TRA = (hA == 0) ? trans_t : (hA == 1) ? trans_p : trans_m;
    const float* TRB = (hB == 0) ? trans_t : (hB == 1) ? trans_p : trans_m;
    int lenA = lens[bA], lenB = lens[bB];
    float trA0 = TRA[lo * 8 + hi], trB0 = TRA[hi * 8 + lo];
    float trA1 = TRB[lo * 8 + hi], trB1 = TRB[hi * 8 + lo];
    const float* l0 = llds[0];
    const float* l1 = llds[1];

    if (wid == 0) {
        // ================ Viterbi wave: 2 interleaved chains ================
        unsigned char* bp0 = (unsigned char*)bpw[0];
        unsigned char* bp1 = (unsigned char*)bpw[1];
        float av0 = l0[lo], av1 = l1[lo];

#define VIT_EVEN(AV, TRX, BPB, t, LT)                                          \
    {                                                                          \
        float v0 = AV + (TRX);                                                 \
        float ra = fmaxf(v0, DPPF(v0, 0xB1));                                  \
        float rb = fmaxf(ra, DPPF(ra, 0x4E));                                  \
        float vmax = fmaxf(rb, DPPF(rb, 0x141));                               \
        unsigned long long mk = __ballot(v0 == vmax);                          \
        int vi = __builtin_ctz(((unsigned)(mk >> (lane & 56))) & 0xffu);       \
        if (lo == 0) BPB[(t) * 8 + hi] = (unsigned char)vi;                    \
        AV = vmax + (LT);                                                      \
    }
#define VIT_ODD(AV, TRX, BPB, t, LT)                                           \
    {                                                                          \
        float v0 = AV + (TRX);                                                 \
        float ra = fmaxf(v0, DPPF(v0, 0x128));                                 \
        float rb = fmaxf(ra, xor16f(ra, lane));                                \
        float vmax = fmaxf(rb, xor32f(rb, lane));                              \
        unsigned long long mk = __ballot(v0 == vmax);                          \
        unsigned long long sel = (mk >> lo) & 0x0101010101010101ULL;           \
        int vi = __builtin_ctzll(sel) >> 3;                                    \
        if (hi == 0) BPB[(t) * 8 + lo] = (unsigned char)vi;                    \
        AV = vmax + (LT);                                                      \
    }

        // 6-step lt pipelines (3 E-slots + 3 O-slots per seq)
        float eA0_0 = l0[1 * 8 + hi], eA0_1 = l0[3 * 8 + hi], eA0_2 = l0[5 * 8 + hi];
        float oA0_0 = l0[2 * 8 + lo], oA0_1 = l0[4 * 8 + lo], oA0_2 = l0[6 * 8 + lo];
        float eA1_0 = l1[1 * 8 + hi], eA1_1 = l1[3 * 8 + hi], eA1_2 = l1[5 * 8 + hi];
        float oA1_0 = l1[2 * 8 + lo], oA1_1 = l1[4 * 8 + lo], oA1_2 = l1[6 * 8 + lo];

        for (int t = 1; t <= 509; t += 2) {
            int te = (t + 6 <= 511) ? (t + 6) : 511;
            int to_ = (t + 7 <= 511) ? (t + 7) : 511;
            float nE0 = l0[te * 8 + hi], nO0 = l0[to_ * 8 + lo];
            float nE1 = l1[te * 8 + hi], nO1 = l1[to_ * 8 + lo];
            VIT_EVEN(av0, trA0, bp0, t, eA0_0)
            VIT_EVEN(av1, trA1, bp1, t, eA1_0)
            VIT_ODD(av0, trB0, bp0, t + 1, oA0_0)
            VIT_ODD(av1, trB1, bp1, t + 1, oA1_0)
            eA0_0 = eA0_1; eA0_1 = eA0_2; eA0_2 = nE0;
            oA0_0 = oA0_1; oA0_1 = oA0_2; oA0_2 = nO0;
            eA1_0 = eA1_1; eA1_1 = eA1_2; eA1_2 = nE1;
            oA1_0 = oA1_1; oA1_1 = oA1_2; oA1_2 = nO1;
        }
        VIT_EVEN(av0, trA0, bp0, 511, eA0_0)
        VIT_EVEN(av1, trA1, bp1, 511, eA1_0)
#undef VIT_EVEN
#undef VIT_ODD

        // per-seq last = argmax (hi-indexed, replicated over lo)
        int last0, last1;
        {
            float ra = fmaxf(av0, DPPF(av0, 0x128));
            float rb = fmaxf(ra, xor16f(ra, lane));
            float vmax = fmaxf(rb, xor32f(rb, lane));
            unsigned long long mk = __ballot(av0 == vmax);
            last0 = __builtin_ctzll(mk) >> 3;
        }
        {
            float ra = fmaxf(av1, DPPF(av1, 0x128));
            float rb = fmaxf(ra, xor16f(ra, lane));
            float vmax = fmaxf(rb, xor32f(rb, lane));
            unsigned long long mk = __ballot(av1 == vmax);
            last1 = __builtin_ctzll(mk) >> 3;
        }

        asm volatile("" ::: "memory");

        // Phase A per seq: compose 8-step bp maps
        int t0 = lane * 8;
        for (int si = 0; si < 2; ++si) {
            unsigned rw[16];
#pragma unroll
            for (int j = 0; j < 8; ++j) {
                int t = t0 + 1 + j;
                if (t <= 511) { rw[2 * j] = bpw[si][t * 2]; rw[2 * j + 1] = bpw[si][t * 2 + 1]; }
                else          { rw[2 * j] = 0x03020100u; rw[2 * j + 1] = 0x07060504u; }
            }
            unsigned sv[8];
#pragma unroll
            for (int i = 0; i < 8; ++i) sv[i] = i;
#pragma unroll
            for (int j = 7; j >= 0; --j) {
                unsigned d0 = rw[2 * j], d1 = rw[2 * j + 1];
#pragma unroll
                for (int i = 0; i < 8; ++i) {
                    unsigned s = sv[i];
                    unsigned d = (s < 4) ? d0 : d1;
                    sv[i] = (d >> (8 * (s & 3))) & 0xffu;
                }
            }
            fmapw[si][lane][0] = sv[0] | (sv[1] << 8) | (sv[2] << 16) | (sv[3] << 24);
            fmapw[si][lane][1] = sv[4] | (sv[5] << 8) | (sv[6] << 16) | (sv[7] << 24);
        }
        asm volatile("" ::: "memory");

        // Phase B: lanes 0/1 walk the two chunk-map chains in parallel
        if (lane < 2) {
            unsigned cur = (unsigned)(lane == 0 ? last0 : last1);
            for (int l = 63; l >= 0; --l) {
                unsigned d = (cur < 4) ? fmapw[lane][l][0] : fmapw[lane][l][1];
                cur = (d >> (8 * (cur & 3))) & 0xffu;
                bnd[lane][l] = (unsigned char)cur;
            }
        }
        asm volatile("" ::: "memory");

        // Phase C per seq: expand + write tags (reload rw)
        for (int si = 0; si < 2; ++si) {
            int hS = si == 0 ? hA : hB;
            int bS = si == 0 ? bA : bB;
            int lastS = si == 0 ? last0 : last1;
            unsigned rw[16];
#pragma unroll
            for (int j = 0; j < 8; ++j) {
                int t = t0 + 1 + j;
                if (t <= 511) { rw[2 * j] = bpw[si][t * 2]; rw[2 * j + 1] = bpw[si][t * 2 + 1]; }
                else          { rw[2 * j] = 0x03020100u; rw[2 * j + 1] = 0x07060504u; }
            }
            int off = hS * 8;
            float* otag = out_tags + bS * (3 * TT) + hS * TT;
            unsigned curr = (lane == 63) ? (unsigned)lastS : (unsigned)bnd[si][lane + 1];
#pragma unroll
            for (int j = 7; j >= 0; --j) {
                unsigned d = (curr < 4) ? rw[2 * j] : rw[2 * j + 1];
                curr = (d >> (8 * (curr & 3))) & 0xffu;
                otag[t0 + j] = (float)((int)curr + off);
            }
        }
    } else {
        // ============ CRF wave: 2 interleaved multiplicative LSEs ============
        const float LN8 = 2.0794415416798357f;
        float EA0 = __expf(trA0), EB0 = __expf(trB0);
        float EA1 = __expf(trA1), EB1 = __expf(trB1);
        float a00 = l0[lo], a01 = l1[lo];
        float c00 = rfl(a00), c01 = rfl(a01);
        float S0 = __expf(a00 - c00), S1 = __expf(a01 - c01);
        float Mc0 = c00, Mc1 = c01;
        float r20 = 0.f, r30 = 0.f, r21 = 0.f, r31 = 0.f;

#define LSE_EVEN(S_, MC, R2, R3, EAx, LEN, t, LT)                              \
    {                                                                          \
        float c = rfl(LT) + LN8;                                               \
        float F = __expf((LT) - c);                                            \
        float P = S_ * (EAx);                                                  \
        float sa = P + DPPF(P, 0xB1);                                          \
        float sb = sa + DPPF(sa, 0x4E);                                        \
        float ss = sb + DPPF(sb, 0x141);                                       \
        if ((t) < (LEN)) { S_ = ss * F; MC += c; }                             \
        R2 = R3; R3 = __logf(rfl(S_));                                         \
    }
#define LSE_ODD(S_, MC, R2, R3, EBx, LEN, t, LT)                               \
    {                                                                          \
        float c = rfl(LT) + LN8;                                               \
        float F = __expf((LT) - c);                                            \
        float P = S_ * (EBx);                                                  \
        float sa = P + DPPF(P, 0x128);                                         \
        float sb = sa + xor16f(sa, lane);                                      \
        float ss = sb + xor32f(sb, lane);                                      \
        if ((t) < (LEN)) { S_ = ss * F; MC += c; }                             \
        R2 = R3; R3 = __logf(rfl(S_));                                         \
    }

        float eA0_0 = l0[1 * 8 + hi], eA0_1 = l0[3 * 8 + hi], eA0_2 = l0[5 * 8 + hi];
        float oA0_0 = l0[2 * 8 + lo], oA0_1 = l0[4 * 8 + lo], oA0_2 = l0[6 * 8 + lo];
        float eA1_0 = l1[1 * 8 + hi], eA1_1 = l1[3 * 8 + hi], eA1_2 = l1[5 * 8 + hi];
        float oA1_0 = l1[2 * 8 + lo], oA1_1 = l1[4 * 8 + lo], oA1_2 = l1[6 * 8 + lo];

        for (int t = 1; t <= 509; t += 2) {
            if ((t & 3) == 1) {                 // exact renorm every 4 steps
                float g0 = r20, g1 = r21;
                S0 *= __expf(-g0); Mc0 += g0;
                S1 *= __expf(-g1); Mc1 += g1;
            }
            int te = (t + 6 <= 511) ? (t + 6) : 511;
            int to_ = (t + 7 <= 511) ? (t + 7) : 511;
            float nE0 = l0[te * 8 + hi], nO0 = l0[to_ * 8 + lo];
            float nE1 = l1[te * 8 + hi], nO1 = l1[to_ * 8 + lo];
            LSE_EVEN(S0, Mc0, r20, r30, EA0, lenA, t, eA0_0)
            LSE_EVEN(S1, Mc1, r21, r31, EA1, lenB, t, eA1_0)
            LSE_ODD(S0, Mc0, r20, r30, EB0, lenA, t + 1, oA0_0)
            LSE_ODD(S1, Mc1, r21, r31, EB1, lenB, t + 1, oA1_0)
            eA0_0 = eA0_1; eA0_1 = eA0_2; eA0_2 = nE0;
            oA0_0 = oA0_1; oA0_1 = oA0_2; oA0_2 = nO0;
            eA1_0 = eA1_1; eA1_1 = eA1_2; eA1_2 = nE1;
            oA1_0 = oA1_1; oA1_1 = oA1_2; oA1_2 = nO1;
        }
        LSE_EVEN(S0, Mc0, r20, r30, EA0, lenA, 511, eA0_0)
        LSE_EVEN(S1, Mc1, r21, r31, EA1, lenB, 511, eA1_0)
#undef LSE_EVEN
#undef LSE_ODD

        // per-seq logZ (reduce over hi field)
        float logZ0, logZ1;
        {
            float aj = Mc0 + __logf(S0);
            float za = fmaxf(aj, DPPF(aj, 0x128));
            float zb = fmaxf(za, xor16f(za, lane));
            float zmax = fmaxf(zb, xor32f(zb, lane));
            float ze = __expf(aj - zmax);
            float zs = ze + DPPF(ze, 0x128);
            float zs2 = zs + xor16f(zs, lane);
            float zsum = zs2 + xor32f(zs2, lane);
            logZ0 = zmax + __logf(zsum);
        }
        {
            float aj = Mc1 + __logf(S1);
            float za = fmaxf(aj, DPPF(aj, 0x128));
            float zb = fmaxf(za, xor16f(za, lane));
            float zmax = fmaxf(zb, xor32f(zb, lane));
            float ze = __expf(aj - zmax);
            float zs = ze + DPPF(ze, 0x128);
            float zs2 = zs + xor16f(zs, lane);
            float zsum = zs2 + xor32f(zs2, lane);
            logZ1 = zmax + __logf(zsum);
        }

        // emit + transition scores for both seqs
        const int* labA = labels + bA * (3 * TT) + hA * TT;
        const int* labB = labels + bB * (3 * TT) + hB * TT;
        int offA = hA * 8, offB = hB * 8;
        float sc0 = 0.f, sc1 = 0.f;
#pragma unroll
        for (int j = 0; j < 8; ++j) {
            int t = lane + 64 * j;
            if (t < lenA) {
                int tg = labA[t] - offA;
                sc0 += l0[t * 8 + tg];
                if (t >= 1) sc0 += TRA[(labA[t - 1] - offA) * 8 + tg];
            }
            if (t < lenB) {
                int tg = labB[t] - offB;
                sc1 += l1[t * 8 + tg];
                if (t >= 1) sc1 += TRB[(labB[t - 1] - offB) * 8 + tg];
            }
        }
#pragma unroll
        for (int d = 1; d <= 32; d <<= 1) { sc0 += __shfl_xor(sc0, d); sc1 += __shfl_xor(sc1, d); }

        if (lane == 0) { partial[sA] = logZ0 - sc0; partial[sB] = logZ1 - sc1; }
    }
}

// ---------------------------------------------------------------------------
// Kernel 3: deterministic loss reduction (192 partials -> scalar)
// ---------------------------------------------------------------------------
__global__ __launch_bounds__(64) void loss_reduce(
    const float* __restrict__ partial, float* __restrict__ out_loss)
{
    int lane = threadIdx.x;
    float s = partial[lane] + partial[lane + 64] + partial[lane + 128];
#pragma unroll
    for (int d = 1; d <= 32; d <<= 1) s += __shfl_xor(s, d);
    if (lane == 0) *out_loss = s;
}

// ---------------------------------------------------------------------------
extern "C" void kernel_launch(void* const* d_in, const int* in_sizes, int n_in,
                              void* d_out, int out_size, void* d_ws, size_t ws_size,
                              hipStream_t stream) {
    const float* enc    = (const float*)d_in[0];
    const int*   labels = (const int*)d_in[1];
    const int*   lens   = (const int*)d_in[2];
    const float* Wt     = (const float*)d_in[3];
    const float* bt     = (const float*)d_in[4];
    const float* Wp     = (const float*)d_in[5];
    const float* bpv    = (const float*)d_in[6];
    const float* Wm     = (const float*)d_in[7];
    const float* bm     = (const float*)d_in[8];
    const float* tr_t   = (const float*)d_in[9];
    const float* tr_p   = (const float*)d_in[10];
    const float* tr_m   = (const float*)d_in[11];

    float* out = (float*)d_out;
    float* lpart = (float*)d_ws;   // 192 floats

    gemm_heads<<<ROWS / 64, 256, 0, stream>>>(enc, Wt, bt, Wp, bpv, Wm, bm, out);
    crf_vit<<<96, 128, 0, stream>>>(out, labels, lens, tr_t, tr_p, tr_m,
                                    out + TAGS_OFF, lpart);
    loss_reduce<<<1, 64, 0, stream>>>(lpart, out + LOSS_OFF);
}

// Round 13
// 86.460 us; speedup vs baseline: 1.5129x; 1.5129x over previous
//
#include <hip/hip_runtime.h>
#include <hip/hip_bf16.h>
#include <math.h>

#define BATCH 64
#define TT 512
#define HH 1024
#define KK 8
#define ROWS (BATCH * TT)          // 32768
#define SEG  (ROWS * KK)           // 262144 floats per logits output
#define TAGS_OFF (3 * SEG)         // 786432
#define LOSS_OFF (TAGS_OFF + BATCH * 3 * TT)  // 884736

// ---------------------------------------------------------------------------
// Kernel 1: fused 3-head GEMM (R11/R12, proven ~35 us at its DS floor; FROZEN).
// ---------------------------------------------------------------------------
__global__ __launch_bounds__(256, 2) void gemm_heads(
    const float* __restrict__ enc,
    const float* __restrict__ Wt, const float* __restrict__ bt,
    const float* __restrict__ Wp, const float* __restrict__ bpv,
    const float* __restrict__ Wm, const float* __restrict__ bm,
    float* __restrict__ out)
{
    __shared__ float xt[4][2][16][68];
    __shared__ float wl[4][2][16][32];
    __shared__ float biasl[24];

    int tid  = threadIdx.x;
    int lane = tid & 63;
    int w    = __builtin_amdgcn_readfirstlane(tid >> 6);
    int r    = lane >> 2;
    int q    = lane & 3;
    int rowblk = blockIdx.x * 64;

    if (tid < 24) {
        int hd = tid >> 3, cl = tid & 7;
        biasl[tid] = (hd == 0) ? bt[cl] : (hd == 1) ? bpv[cl] : bm[cl];
    }

    const float* encw = enc + (size_t)rowblk * HH + w * 256;
    const float* Wkt = Wt + w * 2048;
    const float* Wkp = Wp + w * 2048;
    const float* Wkm = Wm + w * 2048;

    int srow = lane >> 2;
    int schunk = lane & 3;

    float acc[24];
#pragma unroll
    for (int c = 0; c < 24; ++c) acc[c] = 0.f;

    float4 sreg[4];
    float  wreg[6];

#define LOADT(it)                                                             \
    {                                                                         \
        _Pragma("unroll")                                                     \
        for (int i = 0; i < 4; ++i)                                           \
            sreg[i] = *(const float4*)(encw + (size_t)(srow + 16 * i) * HH +  \
                                       (it) * 16 + schunk * 4);               \
    }
#define WRITET(buf)                                                           \
    {                                                                         \
        _Pragma("unroll")                                                     \
        for (int i = 0; i < 4; ++i) {                                         \
            xt[w][buf][schunk * 4 + 0][srow + 16 * i] = sreg[i].x;            \
            xt[w][buf][schunk * 4 + 1][srow + 16 * i] = sreg[i].y;            \
            xt[w][buf][schunk * 4 + 2][srow + 16 * i] = sreg[i].z;            \
            xt[w][buf][schunk * 4 + 3][srow + 16 * i] = sreg[i].w;            \
        }                                                                     \
    }
#define WLOADG(it)                                                            \
    {                                                                         \
        wreg[0] = Wkt[(it) * 128 + lane]; wreg[1] = Wkt[(it) * 128 + 64 + lane]; \
        wreg[2] = Wkp[(it) * 128 + lane]; wreg[3] = Wkp[(it) * 128 + 64 + lane]; \
        wreg[4] = Wkm[(it) * 128 + lane]; wreg[5] = Wkm[(it) * 128 + 64 + lane]; \
    }
#define WWRITE(buf)                                                           \
    {                                                                         \
        int col_ = lane & 7;                                                  \
        _Pragma("unroll")                                                     \
        for (int i = 0; i < 6; ++i) {                                         \
            int hh_ = (lane >> 3) + 8 * (i & 1);                              \
            int c_  = 8 * (i >> 1) + col_;                                    \
            int q_  = (c_ * 43) >> 8;                                         \
            int s_  = c_ - 6 * q_;                                            \
            wl[w][buf][hh_][8 * (q_ ^ (hh_ & 3)) + s_] = wreg[i];             \
        }                                                                     \
    }

    LOADT(0)
    WLOADG(0)
    WRITET(0)
    WWRITE(0)

    for (int it = 0; it < 16; ++it) {
        int cb = it & 1;
        if (it < 15) {
            LOADT(it + 1)
            WLOADG(it + 1)
        }
#pragma unroll
        for (int hh = 0; hh < 16; ++hh) {
            float4 xv = *(const float4*)&xt[w][cb][hh][4 * r];
            const float* wp_ = &wl[w][cb][hh][8 * (q ^ (hh & 3))];
            float4 w0 = *(const float4*)wp_;
            float2 w1 = *(const float2*)(wp_ + 4);
#pragma unroll
            for (int j = 0; j < 4; ++j) {
                float xe = (j == 0) ? xv.x : (j == 1) ? xv.y : (j == 2) ? xv.z : xv.w;
                acc[j * 6 + 0] = fmaf(xe, w0.x, acc[j * 6 + 0]);
                acc[j * 6 + 1] = fmaf(xe, w0.y, acc[j * 6 + 1]);
                acc[j * 6 + 2] = fmaf(xe, w0.z, acc[j * 6 + 2]);
                acc[j * 6 + 3] = fmaf(xe, w0.w, acc[j * 6 + 3]);
                acc[j * 6 + 4] = fmaf(xe, w1.x, acc[j * 6 + 4]);
                acc[j * 6 + 5] = fmaf(xe, w1.y, acc[j * 6 + 5]);
            }
        }
        if (it < 15) {
            WRITET(cb ^ 1)
            WWRITE(cb ^ 1)
        }
    }
#undef LOADT
#undef WRITET
#undef WLOADG
#undef WWRITE

    __syncthreads();
    float* xf = &xt[0][0][0][0];
    int myrow = 4 * r;
    if (w != 0) {
        float* sl = xf + w * 1600;
#pragma unroll
        for (int j = 0; j < 4; ++j)
#pragma unroll
            for (int s = 0; s < 6; ++s)
                sl[(myrow + j) * 25 + q * 6 + s] = acc[j * 6 + s];
    }
    __syncthreads();
    if (w == 0) {
#pragma unroll
        for (int j = 0; j < 4; ++j)
#pragma unroll
            for (int s = 0; s < 6; ++s)
                xf[(myrow + j) * 25 + q * 6 + s] =
                    acc[j * 6 + s] + xf[1600 + (myrow + j) * 25 + q * 6 + s]
                                   + xf[3200 + (myrow + j) * 25 + q * 6 + s]
                                   + xf[4800 + (myrow + j) * 25 + q * 6 + s];
    }
    __syncthreads();
#pragma unroll
    for (int i = 0; i < 2; ++i) {
        int flat = tid + 256 * i;
        if (flat < 384) {
            int seg  = flat >> 7;
            int rem  = flat & 127;
            int row  = rem >> 1;
            int half = rem & 1;
            float4 v;
            v.x = xf[row * 25 + seg * 8 + half * 4 + 0] + biasl[seg * 8 + half * 4 + 0];
            v.y = xf[row * 25 + seg * 8 + half * 4 + 1] + biasl[seg * 8 + half * 4 + 1];
            v.z = xf[row * 25 + seg * 8 + half * 4 + 2] + biasl[seg * 8 + half * 4 + 2];
            v.w = xf[row * 25 + seg * 8 + half * 4 + 3] + biasl[seg * 8 + half * 4 + 3];
            *(float4*)(out + (size_t)seg * SEG + (size_t)(rowblk + row) * 8 + half * 4) = v;
        }
    }
}

// ---------------------------------------------------------------------------
// Pure-VALU cross-lane helpers
// ---------------------------------------------------------------------------
#define DPPF(x, ctrl) __int_as_float(__builtin_amdgcn_update_dpp(              \
    0, __float_as_int(x), ctrl, 0xF, 0xF, true))
#define SWIZF(x, pat) __int_as_float(__builtin_amdgcn_ds_swizzle(              \
    __float_as_int(x), pat))
#define BPERMF(a, x)  __int_as_float(__builtin_amdgcn_ds_bpermute(             \
    a, __float_as_int(x)))

__device__ __forceinline__ float rfl(float x) {
    return __int_as_float(__builtin_amdgcn_readfirstlane(__float_as_int(x)));
}

#if __has_builtin(__builtin_amdgcn_permlane16_swap)
__device__ __forceinline__ float xor16f(float x, int lane) {
    typedef unsigned uv2 __attribute__((ext_vector_type(2)));
    uv2 r = __builtin_amdgcn_permlane16_swap(__float_as_uint(x), __float_as_uint(x), false, false);
    return __uint_as_float((lane & 16) ? r.x : r.y);
}
#else
__device__ __forceinline__ float xor16f(float x, int lane) { return SWIZF(x, 0x401F); }
#endif

#if __has_builtin(__builtin_amdgcn_permlane32_swap)
__device__ __forceinline__ float xor32f(float x, int lane) {
    typedef unsigned uv2 __attribute__((ext_vector_type(2)));
    uv2 r = __builtin_amdgcn_permlane32_swap(__float_as_uint(x), __float_as_uint(x), false, false);
    return __uint_as_float((lane & 32) ? r.x : r.y);
}
#else
__device__ __forceinline__ float xor32f(float x, int lane) {
    return BPERMF(((lane ^ 32) << 2), x);
}
#endif

// ---------------------------------------------------------------------------
// Kernel 2: 192 blocks x 128 threads (2 waves, 1 seq/block).
// Wave 0: VALUES-ONLY Viterbi forward (6-inst steps: add + 3 cross-lane max +
// add + alpha store to LDS) -- no ballot/ctz/exec-mask bp machinery on the
// 511-chain (R12 showed the step is issue-bound, ~2/3 of it bp overhead).
// Backpointers reconstructed afterwards IN PARALLEL from stored alphas
// (bit-exact: same floats, same add, sequential-kp argmax = min-index ties).
// Wave 1: multiplicative LSE with once-per-4-steps renorm bookkeeping
// (per-step log+readfirstlane removed).
// ---------------------------------------------------------------------------
__global__ __launch_bounds__(128) void crf_vit(
    const float* __restrict__ logits,
    const int* __restrict__ labels,
    const int* __restrict__ lens,
    const float* __restrict__ trans_t,
    const float* __restrict__ trans_p,
    const float* __restrict__ trans_m,
    float* __restrict__ out_tags,
    float* __restrict__ partial)
{
    __shared__ float llds[TT * KK];               // 16 KB logits
    __shared__ __align__(16) float alds[TT * KK]; // 16 KB alpha history
    __shared__ unsigned bpw[TT * 2];              // 4 KB backpointers
    __shared__ unsigned fmapw[64][2];
    __shared__ unsigned char bnd[64];

    int blk = blockIdx.x;
    int h   = blk >> 6;
    int b   = blk & 63;
    int tid = threadIdx.x;
    int wid = __builtin_amdgcn_readfirstlane(tid >> 6);
    int lane = tid & 63;
    int hi = lane >> 3, lo = lane & 7;
    unsigned char* bpb = (unsigned char*)bpw;

    const float* L = logits + ((size_t)h * BATCH + b) * (TT * KK);
    const float4* Lv = (const float4*)L;
    float4* lv = (float4*)llds;
#pragma unroll
    for (int i = 0; i < 8; ++i) lv[tid + 128 * i] = Lv[tid + 128 * i];
    __syncthreads();

    const float* TR = (h == 0) ? trans_t : (h == 1) ? trans_p : trans_m;
    int len = lens[b];
    float trA = TR[lo * 8 + hi];   // even step: kp=lo -> kn=hi
    float trB = TR[hi * 8 + lo];   // odd step:  kp=hi -> kn=lo

    if (wid == 0) {
        // ============ Viterbi wave: values-only forward ============
        float av = llds[lo];
        if (lane < 8) alds[lane] = llds[lane];    // alpha_0

#define VSTEP_EVEN(t, LT)                                                      \
    {                                                                          \
        float v0 = av + trA;                                                   \
        float ra = fmaxf(v0, DPPF(v0, 0xB1));                                  \
        float rb = fmaxf(ra, DPPF(ra, 0x4E));                                  \
        float vmax = fmaxf(rb, DPPF(rb, 0x141));                               \
        av = vmax + (LT);                                                      \
        if (lo == 0) alds[(t) * 8 + hi] = av;                                  \
    }
#define VSTEP_ODD(t, LT)                                                       \
    {                                                                          \
        float v0 = av + trB;                                                   \
        float ra = fmaxf(v0, DPPF(v0, 0x128));                                 \
        float rb = fmaxf(ra, xor16f(ra, lane));                                \
        float vmax = fmaxf(rb, xor32f(rb, lane));                              \
        av = vmax + (LT);                                                      \
        if (hi == 0) alds[(t) * 8 + lo] = av;                                  \
    }

        // 2-iteration-deep lt pipeline
        float ltA0 = llds[1 * 8 + hi], ltA1 = llds[3 * 8 + hi];
        float ltB0 = llds[2 * 8 + lo], ltB1 = llds[4 * 8 + lo];
        for (int t = 1; t <= 509; t += 2) {
            int te = (t + 4 <= 511) ? (t + 4) : 511;
            int to_ = (t + 5 <= 511) ? (t + 5) : 511;
            float nE = llds[te * 8 + hi];
            float nO = llds[to_ * 8 + lo];
            VSTEP_EVEN(t, ltA0)
            VSTEP_ODD(t + 1, ltB0)
            ltA0 = ltA1; ltA1 = nE;
            ltB0 = ltB1; ltB1 = nO;
        }
        VSTEP_EVEN(511, ltA0)
#undef VSTEP_EVEN
#undef VSTEP_ODD

        // last = argmax over final alpha (indexed by hi, replicated over lo)
        float ra = fmaxf(av, DPPF(av, 0x128));
        float rb = fmaxf(ra, xor16f(ra, lane));
        float vmax = fmaxf(rb, xor32f(rb, lane));
        unsigned long long mk = __ballot(av == vmax);
        int last_ = __builtin_ctzll(mk) >> 3;

        asm volatile("" ::: "memory");

        // ---- parallel bp reconstruction from alpha history (bit-exact) ----
        {
            int c = lane >> 3;                    // t-chunk 0..7
            int kn = lane & 7;
            float Tk0 = TR[0 * 8 + kn], Tk1 = TR[1 * 8 + kn];
            float Tk2 = TR[2 * 8 + kn], Tk3 = TR[3 * 8 + kn];
            float Tk4 = TR[4 * 8 + kn], Tk5 = TR[5 * 8 + kn];
            float Tk6 = TR[6 * 8 + kn], Tk7 = TR[7 * 8 + kn];
            for (int j = 0; j < 64; ++j) {
                int t = c * 64 + j + 1;
                if (t <= 511) {
                    float4 a03 = *(const float4*)&alds[(t - 1) * 8];
                    float4 a47 = *(const float4*)&alds[(t - 1) * 8 + 4];
                    float v = a03.x + Tk0; int vi = 0; float nv;
                    nv = a03.y + Tk1; if (nv > v) { v = nv; vi = 1; }
                    nv = a03.z + Tk2; if (nv > v) { v = nv; vi = 2; }
                    nv = a03.w + Tk3; if (nv > v) { v = nv; vi = 3; }
                    nv = a47.x + Tk4; if (nv > v) { v = nv; vi = 4; }
                    nv = a47.y + Tk5; if (nv > v) { v = nv; vi = 5; }
                    nv = a47.z + Tk6; if (nv > v) { v = nv; vi = 6; }
                    nv = a47.w + Tk7; if (nv > v) { v = nv; vi = 7; }
                    bpb[t * 8 + kn] = (unsigned char)vi;
                }
            }
        }
        asm volatile("" ::: "memory");

        // Phase A: lane l composes bp maps for t in [8l+1, 8l+8]
        int t0 = lane * 8;
        unsigned rw[16];
#pragma unroll
        for (int j = 0; j < 8; ++j) {
            int t = t0 + 1 + j;
            if (t <= 511) { rw[2 * j] = bpw[t * 2]; rw[2 * j + 1] = bpw[t * 2 + 1]; }
            else          { rw[2 * j] = 0x03020100u; rw[2 * j + 1] = 0x07060504u; }
        }
        unsigned sv[8];
#pragma unroll
        for (int i = 0; i < 8; ++i) sv[i] = i;
#pragma unroll
        for (int j = 7; j >= 0; --j) {
            unsigned d0 = rw[2 * j], d1 = rw[2 * j + 1];
#pragma unroll
            for (int i = 0; i < 8; ++i) {
                unsigned s = sv[i];
                unsigned d = (s < 4) ? d0 : d1;
                sv[i] = (d >> (8 * (s & 3))) & 0xffu;
            }
        }
        fmapw[lane][0] = sv[0] | (sv[1] << 8) | (sv[2] << 16) | (sv[3] << 24);
        fmapw[lane][1] = sv[4] | (sv[5] << 8) | (sv[6] << 16) | (sv[7] << 24);
        asm volatile("" ::: "memory");

        // Phase B: lane 0 walks 64 chunk maps
        if (lane == 0) {
            unsigned cur = (unsigned)last_;
            for (int l = 63; l >= 0; --l) {
                unsigned d = (cur < 4) ? fmapw[l][0] : fmapw[l][1];
                cur = (d >> (8 * (cur & 3))) & 0xffu;
                bnd[l] = (unsigned char)cur;
            }
        }
        asm volatile("" ::: "memory");

        // Phase C: expand within chunk, write tags
        int off = h * 8;
        float* otag = out_tags + b * (3 * TT) + h * TT;
        unsigned curr = (lane == 63) ? (unsigned)last_ : (unsigned)bnd[lane + 1];
#pragma unroll
        for (int j = 7; j >= 0; --j) {
            unsigned d = (curr < 4) ? rw[2 * j] : rw[2 * j + 1];
            curr = (d >> (8 * (curr & 3))) & 0xffu;
            otag[t0 + j] = (float)((int)curr + off);
        }
    } else {
        // ============ CRF wave: multiplicative logsumexp ============
        const float LN8 = 2.0794415416798357f;
        float EA = __expf(trA);
        float EB = __expf(trB);
        float al0 = llds[lo];
        float c0 = rfl(al0);
        float S = __expf(al0 - c0);
        float Mc = c0;
        float g = 0.f;                 // renorm amount, refreshed per renorm

#define LSE_EVEN(t, LT)                                                        \
    {                                                                          \
        float c = rfl(LT) + LN8;                                               \
        float F = __expf((LT) - c);                                            \
        float P = S * EA;                                                      \
        float sa = P + DPPF(P, 0xB1);                                          \
        float sb = sa + DPPF(sa, 0x4E);                                        \
        float ss = sb + DPPF(sb, 0x141);                                       \
        if ((t) < len) { S = ss * F; Mc += c; }                                \
    }
#define LSE_ODD(t, LT)                                                         \
    {                                                                          \
        float c = rfl(LT) + LN8;                                               \
        float F = __expf((LT) - c);                                            \
        float P = S * EB;                                                      \
        float sa = P + DPPF(P, 0x128);                                         \
        float sb = sa + xor16f(sa, lane);                                      \
        float ss = sb + xor32f(sb, lane);                                      \
        if ((t) < len) { S = ss * F; Mc += c; }                                \
    }

        float ltA0 = llds[1 * 8 + hi], ltA1 = llds[3 * 8 + hi];
        float ltB0 = llds[2 * 8 + lo], ltB1 = llds[4 * 8 + lo];
        for (int t = 1; t <= 509; t += 2) {
            if ((t & 3) == 1) {        // exact-bookkeeping renorm, every 4 steps
                S *= __expf(-g);
                Mc += g;
                g = __logf(rfl(S));    // used 4 steps later -> off chain
            }
            int te = (t + 4 <= 511) ? (t + 4) : 511;
            int to_ = (t + 5 <= 511) ? (t + 5) : 511;
            float nE = llds[te * 8 + hi];
            float nO = llds[to_ * 8 + lo];
            LSE_EVEN(t, ltA0)
            LSE_ODD(t + 1, ltB0)
            ltA0 = ltA1; ltA1 = nE;
            ltB0 = ltB1; ltB1 = nO;
        }
        LSE_EVEN(511, ltA0)
#undef LSE_EVEN
#undef LSE_ODD

        float aj = Mc + __logf(S);
        float za = fmaxf(aj, DPPF(aj, 0x128));
        float zb = fmaxf(za, xor16f(za, lane));
        float zmax = fmaxf(zb, xor32f(zb, lane));
        float ze = __expf(aj - zmax);
        float zs = ze + DPPF(ze, 0x128);
        float zs2 = zs + xor16f(zs, lane);
        float zsum = zs2 + xor32f(zs2, lane);
        float logZ = zmax + __logf(zsum);

        const int* lab = labels + b * (3 * TT) + h * TT;
        int off = h * 8;
        float sc = 0.f;
#pragma unroll
        for (int j = 0; j < 8; ++j) {
            int t = lane + 64 * j;
            if (t < len) {
                int tg = lab[t] - off;
                sc += llds[t * 8 + tg];
                if (t >= 1) {
                    int tp = lab[t - 1] - off;
                    sc += TR[tp * 8 + tg];
                }
            }
        }
#pragma unroll
        for (int d = 1; d <= 32; d <<= 1) sc += __shfl_xor(sc, d);

        if (lane == 0) partial[blk] = logZ - sc;
    }
}

// ---------------------------------------------------------------------------
// Kernel 3: deterministic loss reduction (192 partials -> scalar)
// ---------------------------------------------------------------------------
__global__ __launch_bounds__(64) void loss_reduce(
    const float* __restrict__ partial, float* __restrict__ out_loss)
{
    int lane = threadIdx.x;
    float s = partial[lane] + partial[lane + 64] + partial[lane + 128];
#pragma unroll
    for (int d = 1; d <= 32; d <<= 1) s += __shfl_xor(s, d);
    if (lane == 0) *out_loss = s;
}

// ---------------------------------------------------------------------------
extern "C" void kernel_launch(void* const* d_in, const int* in_sizes, int n_in,
                              void* d_out, int out_size, void* d_ws, size_t ws_size,
                              hipStream_t stream) {
    const float* enc    = (const float*)d_in[0];
    const int*   labels = (const int*)d_in[1];
    const int*   lens   = (const int*)d_in[2];
    const float* Wt     = (const float*)d_in[3];
    const float* bt     = (const float*)d_in[4];
    const float* Wp     = (const float*)d_in[5];
    const float* bpv    = (const float*)d_in[6];
    const float* Wm     = (const float*)d_in[7];
    const float* bm     = (const float*)d_in[8];
    const float* tr_t   = (const float*)d_in[9];
    const float* tr_p   = (const float*)d_in[10];
    const float* tr_m   = (const float*)d_in[11];

    float* out = (float*)d_out;
    float* lpart = (float*)d_ws;   // 192 floats

    gemm_heads<<<ROWS / 64, 256, 0, stream>>>(enc, Wt, bt, Wp, bpv, Wm, bm, out);
    crf_vit<<<192, 128, 0, stream>>>(out, labels, lens, tr_t, tr_p, tr_m,
                                     out + TAGS_OFF, lpart);
    loss_reduce<<<1, 64, 0, stream>>>(lpart, out + LOSS_OFF);
}